// Round 10
// baseline (312.856 us; speedup 1.0000x reference)
//
#include <hip/hip_runtime.h>
#include <hip/hip_cooperative_groups.h>
#include <float.h>
#include <math.h>

namespace cg = cooperative_groups;

#define BATCH 8
#define CHN   128
#define NPTS  2048
#define KNN   9
#define NOUT  256
#define TOTCNT (BATCH*NPTS*KNN)

typedef __attribute__((ext_vector_type(8))) short short8;
typedef __attribute__((ext_vector_type(4))) float f32x4;

__device__ __forceinline__ unsigned short f2bf(float f) {
    unsigned int u = __float_as_uint(f);
    unsigned int r = (u + 0x7FFFu + ((u >> 16) & 1u)) >> 16;
    return (unsigned short)r;
}
__device__ __forceinline__ float bf2f(unsigned short h) {
    return __uint_as_float(((unsigned int)h) << 16);
}

// ---------------- kernel 1: transpose + bf16 split + 0.5*sqnorm  (+ fused W split) ----------------
// grid (8 b, 33): y<32 -> x prep tiles (XCD pin via blockIdx.x=b); y==32 -> W split (8-way partition)
__global__ __launch_bounds__(256) void prep_kernel(const float* __restrict__ x,
                                                   const float* __restrict__ W,
                                                   unsigned short* __restrict__ xhi,
                                                   unsigned short* __restrict__ xlo,
                                                   unsigned short* __restrict__ whi,
                                                   unsigned short* __restrict__ wlo,
                                                   float* __restrict__ sqh) {
    __shared__ float xt[128 * 65];
    __shared__ float psq[256];
    const int b = blockIdx.x, tid = threadIdx.x;
    if (blockIdx.y == 32) {   // W -> Bcat=[W1-W2; W2] hi/lo split; rows b*64..b*64+63
#pragma unroll
        for (int e = 0; e < 32; ++e) {
            int idx = e * 256 + tid;
            int r = b * 64 + (idx >> 7), c = idx & 127;
            float v = (r < 256) ? (W[r * 256 + c] - W[r * 256 + 128 + c])
                                : W[(r - 256) * 256 + 128 + c];
            unsigned short h = f2bf(v);
            float hf = bf2f(h);
            whi[r * 128 + c] = h;
            wlo[r * 128 + c] = f2bf(v - hf);
        }
        return;
    }
    const int n0 = blockIdx.y * 64;
#pragma unroll 4
    for (int p = 0; p < 32; ++p) {
        int c = p * 4 + (tid >> 6), n = tid & 63;
        xt[c * 65 + n] = x[((size_t)b * CHN + c) * NPTS + n0 + n];
    }
    __syncthreads();
    const int n = tid >> 2, cq = tid & 3;
    size_t row = (size_t)(b * NPTS + n0 + n) * CHN;
    float s = 0.f;
#pragma unroll 8
    for (int j = 0; j < 32; ++j) {
        int c = cq * 32 + j;
        float f = xt[c * 65 + n];
        unsigned short h = f2bf(f);
        float hf = bf2f(h);
        unsigned short l = f2bf(f - hf);
        xhi[row + c] = h;
        xlo[row + c] = l;
        s += f * f;
    }
    psq[tid] = s;
    __syncthreads();
    if (tid < 64)
        sqh[b * NPTS + n0 + tid] =
            0.5f * (psq[tid*4] + psq[tid*4+1] + psq[tid*4+2] + psq[tid*4+3]);
}

// ---------------- kernel 2: MFMA split-bf16 distance + top-9 (R7 structure, 89us — FROZEN) ----------------
__global__ __launch_bounds__(256) void knn_mfma(const unsigned short* __restrict__ xhi,
                                                const unsigned short* __restrict__ xlo,
                                                const float* __restrict__ sqh,
                                                float* __restrict__ pd,
                                                int* __restrict__ pi) {
    __shared__ __align__(16) float dts[64 * 132];   // 33792 B

    const int tid = threadIdx.x;
    const int b = blockIdx.x, q0 = blockIdx.y * 64, ms = blockIdx.z;
    const int msbase = ms * 512;
    const int wv = tid >> 6, lane = tid & 63;
    const int quad = lane >> 4, col = lane & 15;
    const int koff = quad * 8;
    const int mcol0 = wv * 32;
    const size_t xb = (size_t)b * NPTS * CHN;

    float dl[KNN]; int il[KNN];
#pragma unroll
    for (int k = 0; k < KNN; ++k) { dl[k] = FLT_MAX; il[k] = 0; }

    const int qsc = tid >> 2, ss = tid & 3;
    const int cb = ss * 32;

    auto ins = [&](float v, int idx) {
        if (v < dl[KNN - 1]) {
            bool c0b = v < dl[0];
#pragma unroll
            for (int k = KNN - 1; k >= 1; --k) {
                bool sh   = v < dl[k - 1];
                bool here = v < dl[k];
                float nd = sh ? dl[k - 1] : (here ? v : dl[k]);
                int   ni = sh ? il[k - 1] : (here ? idx : il[k]);
                dl[k] = nd; il[k] = ni;
            }
            if (c0b) { dl[0] = v; il[0] = idx; }
        }
    };

    for (int iter = 0; iter < 4; ++iter) {
        const int mbase = msbase + iter * 128;
        float sm[2];
#pragma unroll
        for (int j = 0; j < 2; ++j)
            sm[j] = sqh[b * NPTS + mbase + mcol0 + j * 16 + col];

        f32x4 acc[4][2];
#pragma unroll
        for (int i = 0; i < 4; ++i)
#pragma unroll
            for (int j = 0; j < 2; ++j) acc[i][j] = (f32x4)0.f;

        for (int chk = 0; chk < 4; ++chk) {
            short8 ah[4], al[4];
#pragma unroll
            for (int i = 0; i < 4; ++i) {
                size_t g = xb + (size_t)(q0 + i * 16 + col) * CHN + chk * 32 + koff;
                ah[i] = *(const short8*)&xhi[g];
                al[i] = *(const short8*)&xlo[g];
            }
#pragma unroll
            for (int j = 0; j < 2; ++j) {
                size_t g = xb + (size_t)(mbase + mcol0 + j * 16 + col) * CHN + chk * 32 + koff;
                short8 bh = *(const short8*)&xhi[g];
                short8 bl = *(const short8*)&xlo[g];
#pragma unroll
                for (int i = 0; i < 4; ++i) {
                    acc[i][j] = __builtin_amdgcn_mfma_f32_16x16x32_bf16(ah[i], bh, acc[i][j], 0, 0, 0);
                    acc[i][j] = __builtin_amdgcn_mfma_f32_16x16x32_bf16(ah[i], bl, acc[i][j], 0, 0, 0);
                    acc[i][j] = __builtin_amdgcn_mfma_f32_16x16x32_bf16(al[i], bh, acc[i][j], 0, 0, 0);
                }
            }
        }

        __syncthreads();
#pragma unroll
        for (int j = 0; j < 2; ++j)
#pragma unroll
            for (int i = 0; i < 4; ++i)
#pragma unroll
                for (int r = 0; r < 4; ++r) {
                    int q_ = i * 16 + quad * 4 + r;
                    dts[q_ * 132 + mcol0 + j * 16 + col] = sm[j] - acc[i][j][r];
                }
        __syncthreads();
        const int ibase = mbase + cb;
#pragma unroll
        for (int jj = 0; jj < 8; ++jj) {
            float4 v = *(const float4*)&dts[qsc * 132 + cb + jj * 4];
            float mn4 = fminf(fminf(v.x, v.y), fminf(v.z, v.w));
            if (mn4 < dl[KNN - 1]) {
                int ib = ibase + jj * 4;
                ins(v.x, ib); ins(v.y, ib + 1); ins(v.z, ib + 2); ins(v.w, ib + 3);
            }
        }
    }

    __syncthreads();
    float* md = dts;
    int*   mi = (int*)(dts + 2304);
#pragma unroll
    for (int k = 0; k < KNN; ++k) {
        md[qsc * 36 + ss * 9 + k] = dl[k];
        mi[qsc * 36 + ss * 9 + k] = il[k];
    }
    __syncthreads();
    if (tid < 64) {
        int base = tid * 36;
        int p0 = 0, p1 = 0, p2 = 0, p3 = 0;
        size_t ob = ((size_t)(b * NPTS + q0 + tid) * 4 + ms) * KNN;
        for (int k = 0; k < KNN; ++k) {
            float v0 = (p0 < KNN) ? md[base + p0]      : FLT_MAX;
            float v1 = (p1 < KNN) ? md[base + 9 + p1]  : FLT_MAX;
            float v2 = (p2 < KNN) ? md[base + 18 + p2] : FLT_MAX;
            float v3 = (p3 < KNN) ? md[base + 27 + p3] : FLT_MAX;
            float best = v0; int sel = 0;
            if (v1 < best) { best = v1; sel = 1; }
            if (v2 < best) { best = v2; sel = 2; }
            if (v3 < best) { best = v3; sel = 3; }
            int idx;
            if      (sel == 0) { idx = mi[base + p0];      p0++; }
            else if (sel == 1) { idx = mi[base + 9 + p1];  p1++; }
            else if (sel == 2) { idx = mi[base + 18 + p2]; p2++; }
            else               { idx = mi[base + 27 + p3]; p3++; }
            pd[ob + k] = best;
            pi[ob + k] = idx;
        }
    }
}

// ---------------- kernel 3: p = x*(W1-W2)^T (fp32), q = x*W2^T (bf16) via MFMA ----------------
// grid (8 b, 8 ntile-of-256, 8 otile-of-64); blockIdx.x = b -> XCD pin. No LDS, no barriers.
__global__ __launch_bounds__(256) void pq_mfma(const unsigned short* __restrict__ xhi,
                                               const unsigned short* __restrict__ xlo,
                                               const unsigned short* __restrict__ whi,
                                               const unsigned short* __restrict__ wlo,
                                               float* __restrict__ p,
                                               unsigned short* __restrict__ q) {
    const int tid = threadIdx.x;
    const int b = blockIdx.x, nt = blockIdx.y, ot = blockIdx.z;
    const int wv = tid >> 6, lane = tid & 63;
    const int quad = lane >> 4, col = lane & 15;
    const int koff = quad * 8;
    const size_t xb = (size_t)b * NPTS * CHN;
    const int nbase = nt * 256 + wv * 64;
    const int obase = ot * 64;

    f32x4 acc[4][4];
#pragma unroll
    for (int i = 0; i < 4; ++i)
#pragma unroll
        for (int j = 0; j < 4; ++j) acc[i][j] = (f32x4)0.f;

    for (int chk = 0; chk < 4; ++chk) {
        short8 ah[4], al[4];
#pragma unroll
        for (int i = 0; i < 4; ++i) {
            size_t g = xb + (size_t)(nbase + i * 16 + col) * CHN + chk * 32 + koff;
            ah[i] = *(const short8*)&xhi[g];
            al[i] = *(const short8*)&xlo[g];
        }
#pragma unroll
        for (int j = 0; j < 4; ++j) {
            size_t g = (size_t)(obase + j * 16 + col) * CHN + chk * 32 + koff;
            short8 bh = *(const short8*)&whi[g];
            short8 bl = *(const short8*)&wlo[g];
#pragma unroll
            for (int i = 0; i < 4; ++i) {
                acc[i][j] = __builtin_amdgcn_mfma_f32_16x16x32_bf16(ah[i], bh, acc[i][j], 0, 0, 0);
                acc[i][j] = __builtin_amdgcn_mfma_f32_16x16x32_bf16(ah[i], bl, acc[i][j], 0, 0, 0);
                acc[i][j] = __builtin_amdgcn_mfma_f32_16x16x32_bf16(al[i], bh, acc[i][j], 0, 0, 0);
            }
        }
    }
#pragma unroll
    for (int i = 0; i < 4; ++i)
#pragma unroll
        for (int j = 0; j < 4; ++j) {
            int oc = (obase + j * 16 + col) & 255;
#pragma unroll
            for (int r = 0; r < 4; ++r) {
                int n = nbase + i * 16 + quad * 4 + r;
                size_t off = (size_t)(b * NPTS + n) * NOUT + oc;
                if (ot < 4) p[off] = acc[i][j][r];
                else        q[off] = f2bf(acc[i][j][r]);
            }
        }
}

// ---------------- kernel 4: COOPERATIVE merge + gather + BN stats + grid-sync + normalize + store ----------------
// grid (8 b, 64 ntile-of-32) = 512 blocks (2/CU co-resident); blockIdx.x = b -> XCD pin.
// Phase 1: merge top-9 lists, gather h = p + q[nn], per-(n,o) max/min -> LDS (bf16),
//          BN partial sums -> global atomics. grid.sync(). Phase 2: normalize + transposed store.
// Removes: hmax rewrite of p (16MB W), hmn buffer (32MB W+R), p re-read (16MB), one dispatch.
__global__ __launch_bounds__(256) void fused_bn_kernel(const float* __restrict__ p,
                                                       const unsigned short* __restrict__ qb,
                                                       const float* __restrict__ pd,
                                                       const int* __restrict__ pi,
                                                       float* __restrict__ stats,
                                                       const float* __restrict__ gamma,
                                                       const float* __restrict__ beta,
                                                       float* __restrict__ out) {
    __shared__ unsigned short hmx_s[32 * 258];   // 16512 B  (bf16 max per (qq,o))
    __shared__ unsigned short hmn_s[32 * 258];   // 16512 B
    __shared__ int   idx_s[32 * KNN];            //  1152 B
    __shared__ float g_s[256], bet_s[256], mean_s[256];  // 3072 B
    const int b = blockIdx.x, n0 = blockIdx.y * 32;
    const int o = threadIdx.x;

    if (threadIdx.x < 32) {     // merge the 4 sorted per-quarter top-9 lists
        size_t g = (size_t)(b * NPTS + n0 + threadIdx.x) * 36;
        const float* d = pd + g;
        const int*   i = pi + g;
        int p0 = 0, p1 = 0, p2 = 0, p3 = 0;
#pragma unroll
        for (int k = 0; k < KNN; ++k) {
            float v0 = (p0 < KNN) ? d[p0]      : FLT_MAX;
            float v1 = (p1 < KNN) ? d[9 + p1]  : FLT_MAX;
            float v2 = (p2 < KNN) ? d[18 + p2] : FLT_MAX;
            float v3 = (p3 < KNN) ? d[27 + p3] : FLT_MAX;
            float best = v0; int sel = 0;
            if (v1 < best) { best = v1; sel = 1; }
            if (v2 < best) { best = v2; sel = 2; }
            if (v3 < best) { best = v3; sel = 3; }
            int idx;
            if      (sel == 0) { idx = i[p0];      p0++; }
            else if (sel == 1) { idx = i[9 + p1];  p1++; }
            else if (sel == 2) { idx = i[18 + p2]; p2++; }
            else               { idx = i[27 + p3]; p3++; }
            idx_s[threadIdx.x * KNN + k] = idx;
        }
    }
    __syncthreads();

    const unsigned short* qbb = qb + (size_t)b * NPTS * NOUT + o;
    float s = 0.f, ss = 0.f;
    for (int qq = 0; qq < 32; ++qq) {
        size_t off = (size_t)(b * NPTS + n0 + qq) * NOUT + o;
        float pv = p[off];
        float mx = -FLT_MAX, mn = FLT_MAX;
#pragma unroll
        for (int k = 0; k < KNN; ++k) {
            float h = pv + bf2f(qbb[(size_t)idx_s[qq * KNN + k] * NOUT]);
            s += h; ss += h * h;
            mx = fmaxf(mx, h); mn = fminf(mn, h);
        }
        hmx_s[qq * 258 + o] = f2bf(mx);
        hmn_s[qq * 258 + o] = f2bf(mn);
    }
    atomicAdd(&stats[o], s);
    atomicAdd(&stats[NOUT + o], ss);
    __threadfence();
    cg::this_grid().sync();

    {   // per-channel BN constants -> LDS
        const float inv = 1.f / (float)TOTCNT;
        float mean = stats[o] * inv;
        float var  = stats[NOUT + o] * inv - mean * mean;
        g_s[o]    = gamma[o] / sqrtf(var + 1e-5f);
        bet_s[o]  = beta[o];
        mean_s[o] = mean;
    }
    __syncthreads();

    const int qq2 = threadIdx.x & 31, og = threadIdx.x >> 5;
#pragma unroll 4
    for (int pass = 0; pass < 32; ++pass) {
        int o_ = pass * 8 + og;
        float g = g_s[o_];
        float v = bf2f((g >= 0.f) ? hmx_s[qq2 * 258 + o_] : hmn_s[qq2 * 258 + o_]);
        float hn = (v - mean_s[o_]) * g + bet_s[o_];
        out[((size_t)b * NOUT + o_) * NPTS + n0 + qq2] = fmaxf(hn, 0.f);
    }
}

extern "C" void kernel_launch(void* const* d_in, const int* in_sizes, int n_in,
                              void* d_out, int out_size, void* d_ws, size_t ws_size,
                              hipStream_t stream) {
    (void)in_sizes; (void)n_in; (void)out_size; (void)ws_size;
    const float* x     = (const float*)d_in[0];
    const float* W     = (const float*)d_in[1];
    const float* gamma = (const float*)d_in[2];
    const float* beta  = (const float*)d_in[3];
    float* out = (float*)d_out;

    char* ws = (char*)d_ws;
    float*          p     = (float*)ws;                                   // 16 MB fp32
    unsigned short* q     = (unsigned short*)(ws + (16u << 20));          // 8 MB bf16
    unsigned short* xhi   = (unsigned short*)(ws + (32u << 20));          // 4 MB
    unsigned short* xlo   = (unsigned short*)(ws + (36u << 20));          // 4 MB
    unsigned short* whi   = (unsigned short*)(ws + (40u << 20));          // 128 KB
    unsigned short* wlo   = (unsigned short*)(ws + (40u << 20) + 131072); // 128 KB
    float*          pd    = (float*)(ws + (48u << 20));                   // 2.25 MB
    int*            pi    = (int*)  (ws + (51u << 20));                   // 2.25 MB
    float*          sqh   = (float*)(ws + (54u << 20));                   // 64 KB
    float*          stats = (float*)(ws + (54u << 20) + 65536);           // 2 KB

    hipMemsetAsync(stats, 0, 2 * NOUT * sizeof(float), stream);
    prep_kernel<<<dim3(8, 33),    256, 0, stream>>>(x, W, xhi, xlo, whi, wlo, sqh);
    knn_mfma   <<<dim3(8, 32, 4), 256, 0, stream>>>(xhi, xlo, sqh, pd, pi);
    pq_mfma    <<<dim3(8, 8, 8),  256, 0, stream>>>(xhi, xlo, whi, wlo, p, q);

    void* fargs[] = { (void*)&p, (void*)&q, (void*)&pd, (void*)&pi,
                      (void*)&stats, (void*)&gamma, (void*)&beta, (void*)&out };
    hipLaunchCooperativeKernel((void*)fused_bn_kernel, dim3(8, 64), dim3(256),
                               fargs, 0, stream);
}

// Round 11
// 272.375 us; speedup vs baseline: 1.1486x; 1.1486x over previous
//
#include <hip/hip_runtime.h>
#include <float.h>
#include <math.h>

#define BATCH 8
#define CHN   128
#define NPTS  2048
#define KNN   9
#define NOUT  256
#define TOTCNT (BATCH*NPTS*KNN)

typedef __attribute__((ext_vector_type(8))) short short8;
typedef __attribute__((ext_vector_type(4))) float f32x4;

__device__ __forceinline__ unsigned short f2bf(float f) {
    unsigned int u = __float_as_uint(f);
    unsigned int r = (u + 0x7FFFu + ((u >> 16) & 1u)) >> 16;
    return (unsigned short)r;
}
__device__ __forceinline__ float bf2f(unsigned short h) {
    return __uint_as_float(((unsigned int)h) << 16);
}

// ---------------- kernel 1: transpose + bf16 split + 0.5*sqnorm  (+ fused W split) ----------------
// grid (8 b, 33): y<32 -> x prep tiles (XCD pin via blockIdx.x=b); y==32 -> W split (8-way partition)
__global__ __launch_bounds__(256) void prep_kernel(const float* __restrict__ x,
                                                   const float* __restrict__ W,
                                                   unsigned short* __restrict__ xhi,
                                                   unsigned short* __restrict__ xlo,
                                                   unsigned short* __restrict__ whi,
                                                   unsigned short* __restrict__ wlo,
                                                   float* __restrict__ sqh) {
    __shared__ float xt[128 * 65];
    __shared__ float psq[256];
    const int b = blockIdx.x, tid = threadIdx.x;
    if (blockIdx.y == 32) {   // W -> Bcat=[W1-W2; W2] hi/lo split; rows b*64..b*64+63
#pragma unroll
        for (int e = 0; e < 32; ++e) {
            int idx = e * 256 + tid;
            int r = b * 64 + (idx >> 7), c = idx & 127;
            float v = (r < 256) ? (W[r * 256 + c] - W[r * 256 + 128 + c])
                                : W[(r - 256) * 256 + 128 + c];
            unsigned short h = f2bf(v);
            float hf = bf2f(h);
            whi[r * 128 + c] = h;
            wlo[r * 128 + c] = f2bf(v - hf);
        }
        return;
    }
    const int n0 = blockIdx.y * 64;
#pragma unroll 4
    for (int p = 0; p < 32; ++p) {
        int c = p * 4 + (tid >> 6), n = tid & 63;
        xt[c * 65 + n] = x[((size_t)b * CHN + c) * NPTS + n0 + n];
    }
    __syncthreads();
    const int n = tid >> 2, cq = tid & 3;
    size_t row = (size_t)(b * NPTS + n0 + n) * CHN;
    float s = 0.f;
#pragma unroll 8
    for (int j = 0; j < 32; ++j) {
        int c = cq * 32 + j;
        float f = xt[c * 65 + n];
        unsigned short h = f2bf(f);
        float hf = bf2f(h);
        unsigned short l = f2bf(f - hf);
        xhi[row + c] = h;
        xlo[row + c] = l;
        s += f * f;
    }
    psq[tid] = s;
    __syncthreads();
    if (tid < 64)
        sqh[b * NPTS + n0 + tid] =
            0.5f * (psq[tid*4] + psq[tid*4+1] + psq[tid*4+2] + psq[tid*4+3]);
}

// ---------------- kernel 2: FUSED knn (R7 structure) + pq — independent work, one dispatch ----------------
// grid (8 b, 32, 6): z<4 -> knn m-quarter z; z>=4 -> pq block (nt = y>>2, ot = ((y&3)<<1)|(z-4)).
// pq blocks backfill CUs while knn's latency-bound blocks stall (knn alone: 19% occ, 50% idle).
__global__ __launch_bounds__(256) void knnpq_mfma(const unsigned short* __restrict__ xhi,
                                                  const unsigned short* __restrict__ xlo,
                                                  const float* __restrict__ sqh,
                                                  const unsigned short* __restrict__ whi,
                                                  const unsigned short* __restrict__ wlo,
                                                  float* __restrict__ pd,
                                                  int* __restrict__ pi,
                                                  float* __restrict__ p,
                                                  float* __restrict__ q) {
    __shared__ __align__(16) float dts[64 * 132];   // 33792 B (knn path only)

    const int tid = threadIdx.x;
    const int b = blockIdx.x;
    const int wv = tid >> 6, lane = tid & 63;
    const int quad = lane >> 4, col = lane & 15;
    const int koff = quad * 8;
    const size_t xb = (size_t)b * NPTS * CHN;

    if (blockIdx.z >= 4) {
        // ---------------- pq path: p = x*(W1-W2)^T, q = x*W2^T ----------------
        const int nt = blockIdx.y >> 2;
        const int ot = ((blockIdx.y & 3) << 1) | (blockIdx.z - 4);
        const int nbase = nt * 256 + wv * 64;
        const int obase = ot * 64;

        f32x4 acc[4][4];
#pragma unroll
        for (int i = 0; i < 4; ++i)
#pragma unroll
            for (int j = 0; j < 4; ++j) acc[i][j] = (f32x4)0.f;

        for (int chk = 0; chk < 4; ++chk) {
            short8 ah[4], al[4];
#pragma unroll
            for (int i = 0; i < 4; ++i) {
                size_t g = xb + (size_t)(nbase + i * 16 + col) * CHN + chk * 32 + koff;
                ah[i] = *(const short8*)&xhi[g];
                al[i] = *(const short8*)&xlo[g];
            }
#pragma unroll
            for (int j = 0; j < 4; ++j) {
                size_t g = (size_t)(obase + j * 16 + col) * CHN + chk * 32 + koff;
                short8 bh = *(const short8*)&whi[g];
                short8 bl = *(const short8*)&wlo[g];
#pragma unroll
                for (int i = 0; i < 4; ++i) {
                    acc[i][j] = __builtin_amdgcn_mfma_f32_16x16x32_bf16(ah[i], bh, acc[i][j], 0, 0, 0);
                    acc[i][j] = __builtin_amdgcn_mfma_f32_16x16x32_bf16(ah[i], bl, acc[i][j], 0, 0, 0);
                    acc[i][j] = __builtin_amdgcn_mfma_f32_16x16x32_bf16(al[i], bh, acc[i][j], 0, 0, 0);
                }
            }
        }
        float* dst = (ot < 4) ? p : q;
#pragma unroll
        for (int i = 0; i < 4; ++i)
#pragma unroll
            for (int j = 0; j < 4; ++j) {
                int oc = (obase + j * 16 + col) & 255;
#pragma unroll
                for (int r = 0; r < 4; ++r) {
                    int n = nbase + i * 16 + quad * 4 + r;
                    dst[(size_t)(b * NPTS + n) * NOUT + oc] = acc[i][j][r];
                }
            }
        return;
    }

    // ---------------- knn path (R7 structure, 89us — FROZEN) ----------------
    const int q0 = blockIdx.y * 64, ms = blockIdx.z;
    const int msbase = ms * 512;
    const int mcol0 = wv * 32;

    float dl[KNN]; int il[KNN];
#pragma unroll
    for (int k = 0; k < KNN; ++k) { dl[k] = FLT_MAX; il[k] = 0; }

    const int qsc = tid >> 2, ss = tid & 3;
    const int cb = ss * 32;

    auto ins = [&](float v, int idx) {
        if (v < dl[KNN - 1]) {
            bool c0b = v < dl[0];
#pragma unroll
            for (int k = KNN - 1; k >= 1; --k) {
                bool sh   = v < dl[k - 1];
                bool here = v < dl[k];
                float nd = sh ? dl[k - 1] : (here ? v : dl[k]);
                int   ni = sh ? il[k - 1] : (here ? idx : il[k]);
                dl[k] = nd; il[k] = ni;
            }
            if (c0b) { dl[0] = v; il[0] = idx; }
        }
    };

    for (int iter = 0; iter < 4; ++iter) {
        const int mbase = msbase + iter * 128;
        float sm[2];
#pragma unroll
        for (int j = 0; j < 2; ++j)
            sm[j] = sqh[b * NPTS + mbase + mcol0 + j * 16 + col];

        f32x4 acc[4][2];
#pragma unroll
        for (int i = 0; i < 4; ++i)
#pragma unroll
            for (int j = 0; j < 2; ++j) acc[i][j] = (f32x4)0.f;

        for (int chk = 0; chk < 4; ++chk) {
            short8 ah[4], al[4];
#pragma unroll
            for (int i = 0; i < 4; ++i) {
                size_t g = xb + (size_t)(q0 + i * 16 + col) * CHN + chk * 32 + koff;
                ah[i] = *(const short8*)&xhi[g];
                al[i] = *(const short8*)&xlo[g];
            }
#pragma unroll
            for (int j = 0; j < 2; ++j) {
                size_t g = xb + (size_t)(mbase + mcol0 + j * 16 + col) * CHN + chk * 32 + koff;
                short8 bh = *(const short8*)&xhi[g];
                short8 bl = *(const short8*)&xlo[g];
#pragma unroll
                for (int i = 0; i < 4; ++i) {
                    acc[i][j] = __builtin_amdgcn_mfma_f32_16x16x32_bf16(ah[i], bh, acc[i][j], 0, 0, 0);
                    acc[i][j] = __builtin_amdgcn_mfma_f32_16x16x32_bf16(ah[i], bl, acc[i][j], 0, 0, 0);
                    acc[i][j] = __builtin_amdgcn_mfma_f32_16x16x32_bf16(al[i], bh, acc[i][j], 0, 0, 0);
                }
            }
        }

        __syncthreads();
#pragma unroll
        for (int j = 0; j < 2; ++j)
#pragma unroll
            for (int i = 0; i < 4; ++i)
#pragma unroll
                for (int r = 0; r < 4; ++r) {
                    int q_ = i * 16 + quad * 4 + r;
                    dts[q_ * 132 + mcol0 + j * 16 + col] = sm[j] - acc[i][j][r];
                }
        __syncthreads();
        const int ibase = mbase + cb;
#pragma unroll
        for (int jj = 0; jj < 8; ++jj) {
            float4 v = *(const float4*)&dts[qsc * 132 + cb + jj * 4];
            float mn4 = fminf(fminf(v.x, v.y), fminf(v.z, v.w));
            if (mn4 < dl[KNN - 1]) {
                int ib = ibase + jj * 4;
                ins(v.x, ib); ins(v.y, ib + 1); ins(v.z, ib + 2); ins(v.w, ib + 3);
            }
        }
    }

    __syncthreads();
    float* md = dts;
    int*   mi = (int*)(dts + 2304);
#pragma unroll
    for (int k = 0; k < KNN; ++k) {
        md[qsc * 36 + ss * 9 + k] = dl[k];
        mi[qsc * 36 + ss * 9 + k] = il[k];
    }
    __syncthreads();
    if (tid < 64) {
        int base = tid * 36;
        int p0 = 0, p1 = 0, p2 = 0, p3 = 0;
        size_t ob = ((size_t)(b * NPTS + q0 + tid) * 4 + ms) * KNN;
        for (int k = 0; k < KNN; ++k) {
            float v0 = (p0 < KNN) ? md[base + p0]      : FLT_MAX;
            float v1 = (p1 < KNN) ? md[base + 9 + p1]  : FLT_MAX;
            float v2 = (p2 < KNN) ? md[base + 18 + p2] : FLT_MAX;
            float v3 = (p3 < KNN) ? md[base + 27 + p3] : FLT_MAX;
            float best = v0; int sel = 0;
            if (v1 < best) { best = v1; sel = 1; }
            if (v2 < best) { best = v2; sel = 2; }
            if (v3 < best) { best = v3; sel = 3; }
            int idx;
            if      (sel == 0) { idx = mi[base + p0];      p0++; }
            else if (sel == 1) { idx = mi[base + 9 + p1];  p1++; }
            else if (sel == 2) { idx = mi[base + 18 + p2]; p2++; }
            else               { idx = mi[base + 27 + p3]; p3++; }
            pd[ob + k] = best;
            pi[ob + k] = idx;
        }
    }
}

// ---------------- kernel 3: merge FUSED + BN stats + per-(n,o) max/min ----------------
// grid (8 b, 128 ntile-of-16) = 1024 blocks (4/CU, 16 waves/CU); blockIdx.x = b -> XCD pin.
// 2-query unroll: 18 independent q-row gathers + 2 p loads in flight per step
// (R10 post-mortem: gather latency serialization at VGPR 52 / 8 waves/CU was the tail's core).
__global__ __launch_bounds__(256) void stats2_kernel(float* __restrict__ p,
                                                     const float* __restrict__ q,
                                                     const float* __restrict__ pd,
                                                     const int* __restrict__ pi,
                                                     float* __restrict__ stats,
                                                     float* __restrict__ hmn) {
    __shared__ int idx_s[16 * KNN];
    const int b = blockIdx.x, n0 = blockIdx.y * 16;
    const int o = threadIdx.x;
    if (threadIdx.x < 16) {
        size_t g = (size_t)(b * NPTS + n0 + threadIdx.x) * 36;
        const float* d = pd + g;
        const int*   i = pi + g;
        int p0 = 0, p1 = 0, p2 = 0, p3 = 0;
#pragma unroll
        for (int k = 0; k < KNN; ++k) {
            float v0 = (p0 < KNN) ? d[p0]      : FLT_MAX;
            float v1 = (p1 < KNN) ? d[9 + p1]  : FLT_MAX;
            float v2 = (p2 < KNN) ? d[18 + p2] : FLT_MAX;
            float v3 = (p3 < KNN) ? d[27 + p3] : FLT_MAX;
            float best = v0; int sel = 0;
            if (v1 < best) { best = v1; sel = 1; }
            if (v2 < best) { best = v2; sel = 2; }
            if (v3 < best) { best = v3; sel = 3; }
            int idx;
            if      (sel == 0) { idx = i[p0];      p0++; }
            else if (sel == 1) { idx = i[9 + p1];  p1++; }
            else if (sel == 2) { idx = i[18 + p2]; p2++; }
            else               { idx = i[27 + p3]; p3++; }
            idx_s[threadIdx.x * KNN + k] = idx;
        }
    }
    __syncthreads();
    const float* qb = q + (size_t)b * NPTS * NOUT + o;
    float s = 0.f, ss = 0.f;
    for (int qq = 0; qq < 16; qq += 2) {
        size_t off0 = (size_t)(b * NPTS + n0 + qq) * NOUT + o;
        size_t off1 = off0 + NOUT;
        float pv0 = p[off0], pv1 = p[off1];
        float h0[KNN], h1[KNN];
#pragma unroll
        for (int k = 0; k < KNN; ++k)
            h0[k] = qb[(size_t)idx_s[qq * KNN + k] * NOUT];
#pragma unroll
        for (int k = 0; k < KNN; ++k)
            h1[k] = qb[(size_t)idx_s[(qq + 1) * KNN + k] * NOUT];
        float mx0 = -FLT_MAX, mn0 = FLT_MAX, mx1 = -FLT_MAX, mn1 = FLT_MAX;
#pragma unroll
        for (int k = 0; k < KNN; ++k) {
            float a = pv0 + h0[k], c = pv1 + h1[k];
            s += a + c; ss += a * a + c * c;
            mx0 = fmaxf(mx0, a); mn0 = fminf(mn0, a);
            mx1 = fmaxf(mx1, c); mn1 = fminf(mn1, c);
        }
        p[off0] = mx0; hmn[off0] = mn0;
        p[off1] = mx1; hmn[off1] = mn1;
    }
    atomicAdd(&stats[o], s);
    atomicAdd(&stats[NOUT + o], ss);
}

// ---------------- kernel 4: normalize + relu + max_k, transposed store ----------------
// grid (8 b, 128 ntile-of-16); blockIdx.x = b -> XCD pin. Pointer-select before load.
__global__ __launch_bounds__(256) void final_kernel(const float* __restrict__ hmx,
                                                    const float* __restrict__ hmn,
                                                    const float* __restrict__ stats,
                                                    const float* __restrict__ gamma,
                                                    const float* __restrict__ beta,
                                                    float* __restrict__ out) {
    __shared__ float tr[256 * 17];
    const int b = blockIdx.x, n0 = blockIdx.y * 16;
    const int o = threadIdx.x;
    const float inv = 1.f / (float)TOTCNT;
    float mean = stats[o] * inv;
    float var  = stats[NOUT + o] * inv - mean * mean;
    float g    = gamma[o] / sqrtf(var + 1e-5f);
    float bet  = beta[o];
    const float* src = (g >= 0.f) ? hmx : hmn;
    for (int qq = 0; qq < 16; ++qq) {
        size_t off = (size_t)(b * NPTS + n0 + qq) * NOUT + o;
        float hn = (src[off] - mean) * g + bet;
        tr[o * 17 + qq] = fmaxf(hn, 0.f);
    }
    __syncthreads();
    int oo = threadIdx.x >> 4, qq = threadIdx.x & 15;
    for (int pass = 0; pass < 16; ++pass) {
        int o_ = pass * 16 + oo;
        out[((size_t)b * NOUT + o_) * NPTS + n0 + qq] = tr[o_ * 17 + qq];
    }
}

extern "C" void kernel_launch(void* const* d_in, const int* in_sizes, int n_in,
                              void* d_out, int out_size, void* d_ws, size_t ws_size,
                              hipStream_t stream) {
    (void)in_sizes; (void)n_in; (void)out_size; (void)ws_size;
    const float* x     = (const float*)d_in[0];
    const float* W     = (const float*)d_in[1];
    const float* gamma = (const float*)d_in[2];
    const float* beta  = (const float*)d_in[3];
    float* out = (float*)d_out;

    char* ws = (char*)d_ws;
    // [0,16M)  p  -> becomes hmax in stats2 (in-place)
    // [16,32M) q  (fp32)
    // [32,48M) knn/pq scratch (xhi,xlo,whi,wlo) -> dead by stats2, reused as hmn
    // [48M+)   pd, pi (live into stats2), sqh, stats
    float*          p     = (float*)ws;
    float*          q     = (float*)(ws + (16u << 20));
    unsigned short* xhi   = (unsigned short*)(ws + (32u << 20));          // 4 MB
    unsigned short* xlo   = (unsigned short*)(ws + (36u << 20));          // 4 MB
    unsigned short* whi   = (unsigned short*)(ws + (40u << 20));          // 128 KB
    unsigned short* wlo   = (unsigned short*)(ws + (40u << 20) + 131072); // 128 KB
    float*          hmn   = (float*)(ws + (32u << 20));                   // 16 MB overlay
    float*          pd    = (float*)(ws + (48u << 20));                   // 2.25 MB
    int*            pi    = (int*)  (ws + (51u << 20));                   // 2.25 MB
    float*          sqh   = (float*)(ws + (54u << 20));                   // 64 KB
    float*          stats = (float*)(ws + (54u << 20) + 65536);           // 2 KB

    hipMemsetAsync(stats, 0, 2 * NOUT * sizeof(float), stream);
    prep_kernel  <<<dim3(8, 33),    256, 0, stream>>>(x, W, xhi, xlo, whi, wlo, sqh);
    knnpq_mfma   <<<dim3(8, 32, 6), 256, 0, stream>>>(xhi, xlo, sqh, whi, wlo, pd, pi, p, q);
    stats2_kernel<<<dim3(8, 128),   256, 0, stream>>>(p, q, pd, pi, stats, hmn);
    final_kernel <<<dim3(8, 128),   256, 0, stream>>>(p, hmn, stats, gamma, beta, out);
}

// Round 12
// 213.091 us; speedup vs baseline: 1.4682x; 1.2782x over previous
//
#include <hip/hip_runtime.h>
#include <float.h>
#include <math.h>

#define BATCH 8
#define CHN   128
#define NPTS  2048
#define KNN   9
#define NOUT  256
#define TOTCNT (BATCH*NPTS*KNN)

typedef __attribute__((ext_vector_type(8))) short short8;
typedef __attribute__((ext_vector_type(4))) float f32x4;

__device__ __forceinline__ unsigned short f2bf(float f) {
    unsigned int u = __float_as_uint(f);
    unsigned int r = (u + 0x7FFFu + ((u >> 16) & 1u)) >> 16;
    return (unsigned short)r;
}
__device__ __forceinline__ float bf2f(unsigned short h) {
    return __uint_as_float(((unsigned int)h) << 16);
}

// ---------------- kernel 1: transpose + bf16 split + 0.5*sqnorm  (+ fused W split) ----------------
// grid (8 b, 33): y<32 -> x prep tiles (XCD pin via blockIdx.x=b); y==32 -> W split (8-way partition)
__global__ __launch_bounds__(256) void prep_kernel(const float* __restrict__ x,
                                                   const float* __restrict__ W,
                                                   unsigned short* __restrict__ xhi,
                                                   unsigned short* __restrict__ xlo,
                                                   unsigned short* __restrict__ whi,
                                                   unsigned short* __restrict__ wlo,
                                                   float* __restrict__ sqh) {
    __shared__ float xt[128 * 65];
    __shared__ float psq[256];
    const int b = blockIdx.x, tid = threadIdx.x;
    if (blockIdx.y == 32) {   // W -> Bcat=[W1-W2; W2] hi/lo split; rows b*64..b*64+63
#pragma unroll
        for (int e = 0; e < 32; ++e) {
            int idx = e * 256 + tid;
            int r = b * 64 + (idx >> 7), c = idx & 127;
            float v = (r < 256) ? (W[r * 256 + c] - W[r * 256 + 128 + c])
                                : W[(r - 256) * 256 + 128 + c];
            unsigned short h = f2bf(v);
            float hf = bf2f(h);
            whi[r * 128 + c] = h;
            wlo[r * 128 + c] = f2bf(v - hf);
        }
        return;
    }
    const int n0 = blockIdx.y * 64;
#pragma unroll 4
    for (int p = 0; p < 32; ++p) {
        int c = p * 4 + (tid >> 6), n = tid & 63;
        xt[c * 65 + n] = x[((size_t)b * CHN + c) * NPTS + n0 + n];
    }
    __syncthreads();
    const int n = tid >> 2, cq = tid & 3;
    size_t row = (size_t)(b * NPTS + n0 + n) * CHN;
    float s = 0.f;
#pragma unroll 8
    for (int j = 0; j < 32; ++j) {
        int c = cq * 32 + j;
        float f = xt[c * 65 + n];
        unsigned short h = f2bf(f);
        float hf = bf2f(h);
        unsigned short l = f2bf(f - hf);
        xhi[row + c] = h;
        xlo[row + c] = l;
        s += f * f;
    }
    psq[tid] = s;
    __syncthreads();
    if (tid < 64)
        sqh[b * NPTS + n0 + tid] =
            0.5f * (psq[tid*4] + psq[tid*4+1] + psq[tid*4+2] + psq[tid*4+3]);
}

// ---------------- kernel 2: MFMA split-bf16 distance + top-9 (R7 structure, 89us — FROZEN) ----------------
// Standalone dispatch (R11 fusion with pq shared the worst-case 148-reg allocation -> regressed).
__global__ __launch_bounds__(256) void knn_mfma(const unsigned short* __restrict__ xhi,
                                                const unsigned short* __restrict__ xlo,
                                                const float* __restrict__ sqh,
                                                float* __restrict__ pd,
                                                int* __restrict__ pi) {
    __shared__ __align__(16) float dts[64 * 132];   // 33792 B

    const int tid = threadIdx.x;
    const int b = blockIdx.x, q0 = blockIdx.y * 64, ms = blockIdx.z;
    const int msbase = ms * 512;
    const int wv = tid >> 6, lane = tid & 63;
    const int quad = lane >> 4, col = lane & 15;
    const int koff = quad * 8;
    const int mcol0 = wv * 32;
    const size_t xb = (size_t)b * NPTS * CHN;

    float dl[KNN]; int il[KNN];
#pragma unroll
    for (int k = 0; k < KNN; ++k) { dl[k] = FLT_MAX; il[k] = 0; }

    const int qsc = tid >> 2, ss = tid & 3;
    const int cb = ss * 32;

    auto ins = [&](float v, int idx) {
        if (v < dl[KNN - 1]) {
            bool c0b = v < dl[0];
#pragma unroll
            for (int k = KNN - 1; k >= 1; --k) {
                bool sh   = v < dl[k - 1];
                bool here = v < dl[k];
                float nd = sh ? dl[k - 1] : (here ? v : dl[k]);
                int   ni = sh ? il[k - 1] : (here ? idx : il[k]);
                dl[k] = nd; il[k] = ni;
            }
            if (c0b) { dl[0] = v; il[0] = idx; }
        }
    };

    for (int iter = 0; iter < 4; ++iter) {
        const int mbase = msbase + iter * 128;
        float sm[2];
#pragma unroll
        for (int j = 0; j < 2; ++j)
            sm[j] = sqh[b * NPTS + mbase + mcol0 + j * 16 + col];

        f32x4 acc[4][2];
#pragma unroll
        for (int i = 0; i < 4; ++i)
#pragma unroll
            for (int j = 0; j < 2; ++j) acc[i][j] = (f32x4)0.f;

        for (int chk = 0; chk < 4; ++chk) {
            short8 ah[4], al[4];
#pragma unroll
            for (int i = 0; i < 4; ++i) {
                size_t g = xb + (size_t)(q0 + i * 16 + col) * CHN + chk * 32 + koff;
                ah[i] = *(const short8*)&xhi[g];
                al[i] = *(const short8*)&xlo[g];
            }
#pragma unroll
            for (int j = 0; j < 2; ++j) {
                size_t g = xb + (size_t)(mbase + mcol0 + j * 16 + col) * CHN + chk * 32 + koff;
                short8 bh = *(const short8*)&xhi[g];
                short8 bl = *(const short8*)&xlo[g];
#pragma unroll
                for (int i = 0; i < 4; ++i) {
                    acc[i][j] = __builtin_amdgcn_mfma_f32_16x16x32_bf16(ah[i], bh, acc[i][j], 0, 0, 0);
                    acc[i][j] = __builtin_amdgcn_mfma_f32_16x16x32_bf16(ah[i], bl, acc[i][j], 0, 0, 0);
                    acc[i][j] = __builtin_amdgcn_mfma_f32_16x16x32_bf16(al[i], bh, acc[i][j], 0, 0, 0);
                }
            }
        }

        __syncthreads();
#pragma unroll
        for (int j = 0; j < 2; ++j)
#pragma unroll
            for (int i = 0; i < 4; ++i)
#pragma unroll
                for (int r = 0; r < 4; ++r) {
                    int q_ = i * 16 + quad * 4 + r;
                    dts[q_ * 132 + mcol0 + j * 16 + col] = sm[j] - acc[i][j][r];
                }
        __syncthreads();
        const int ibase = mbase + cb;
#pragma unroll
        for (int jj = 0; jj < 8; ++jj) {
            float4 v = *(const float4*)&dts[qsc * 132 + cb + jj * 4];
            float mn4 = fminf(fminf(v.x, v.y), fminf(v.z, v.w));
            if (mn4 < dl[KNN - 1]) {
                int ib = ibase + jj * 4;
                ins(v.x, ib); ins(v.y, ib + 1); ins(v.z, ib + 2); ins(v.w, ib + 3);
            }
        }
    }

    __syncthreads();
    float* md = dts;
    int*   mi = (int*)(dts + 2304);
#pragma unroll
    for (int k = 0; k < KNN; ++k) {
        md[qsc * 36 + ss * 9 + k] = dl[k];
        mi[qsc * 36 + ss * 9 + k] = il[k];
    }
    __syncthreads();
    if (tid < 64) {
        int base = tid * 36;
        int p0 = 0, p1 = 0, p2 = 0, p3 = 0;
        size_t ob = ((size_t)(b * NPTS + q0 + tid) * 4 + ms) * KNN;
        for (int k = 0; k < KNN; ++k) {
            float v0 = (p0 < KNN) ? md[base + p0]      : FLT_MAX;
            float v1 = (p1 < KNN) ? md[base + 9 + p1]  : FLT_MAX;
            float v2 = (p2 < KNN) ? md[base + 18 + p2] : FLT_MAX;
            float v3 = (p3 < KNN) ? md[base + 27 + p3] : FLT_MAX;
            float best = v0; int sel = 0;
            if (v1 < best) { best = v1; sel = 1; }
            if (v2 < best) { best = v2; sel = 2; }
            if (v3 < best) { best = v3; sel = 3; }
            int idx;
            if      (sel == 0) { idx = mi[base + p0];      p0++; }
            else if (sel == 1) { idx = mi[base + 9 + p1];  p1++; }
            else if (sel == 2) { idx = mi[base + 18 + p2]; p2++; }
            else               { idx = mi[base + 27 + p3]; p3++; }
            pd[ob + k] = best;
            pi[ob + k] = idx;
        }
    }
}

// ---------------- kernel 3: p = x*(W1-W2)^T, q = x*W2^T via MFMA (R9-proven) ----------------
// grid (8 b, 8 ntile-of-256, 8 otile-of-64); blockIdx.x = b -> XCD pin. No LDS, no barriers.
__global__ __launch_bounds__(256) void pq_mfma(const unsigned short* __restrict__ xhi,
                                               const unsigned short* __restrict__ xlo,
                                               const unsigned short* __restrict__ whi,
                                               const unsigned short* __restrict__ wlo,
                                               float* __restrict__ p,
                                               float* __restrict__ q) {
    const int tid = threadIdx.x;
    const int b = blockIdx.x, nt = blockIdx.y, ot = blockIdx.z;
    const int wv = tid >> 6, lane = tid & 63;
    const int quad = lane >> 4, col = lane & 15;
    const int koff = quad * 8;
    const size_t xb = (size_t)b * NPTS * CHN;
    const int nbase = nt * 256 + wv * 64;
    const int obase = ot * 64;

    f32x4 acc[4][4];
#pragma unroll
    for (int i = 0; i < 4; ++i)
#pragma unroll
        for (int j = 0; j < 4; ++j) acc[i][j] = (f32x4)0.f;

    for (int chk = 0; chk < 4; ++chk) {
        short8 ah[4], al[4];
#pragma unroll
        for (int i = 0; i < 4; ++i) {
            size_t g = xb + (size_t)(nbase + i * 16 + col) * CHN + chk * 32 + koff;
            ah[i] = *(const short8*)&xhi[g];
            al[i] = *(const short8*)&xlo[g];
        }
#pragma unroll
        for (int j = 0; j < 4; ++j) {
            size_t g = (size_t)(obase + j * 16 + col) * CHN + chk * 32 + koff;
            short8 bh = *(const short8*)&whi[g];
            short8 bl = *(const short8*)&wlo[g];
#pragma unroll
            for (int i = 0; i < 4; ++i) {
                acc[i][j] = __builtin_amdgcn_mfma_f32_16x16x32_bf16(ah[i], bh, acc[i][j], 0, 0, 0);
                acc[i][j] = __builtin_amdgcn_mfma_f32_16x16x32_bf16(ah[i], bl, acc[i][j], 0, 0, 0);
                acc[i][j] = __builtin_amdgcn_mfma_f32_16x16x32_bf16(al[i], bh, acc[i][j], 0, 0, 0);
            }
        }
    }
    float* dst = (ot < 4) ? p : q;
#pragma unroll
    for (int i = 0; i < 4; ++i)
#pragma unroll
        for (int j = 0; j < 4; ++j) {
            int oc = (obase + j * 16 + col) & 255;
#pragma unroll
            for (int r = 0; r < 4; ++r) {
                int n = nbase + i * 16 + quad * 4 + r;
                dst[(size_t)(b * NPTS + n) * NOUT + oc] = acc[i][j][r];
            }
        }
}

// ---------------- kernel 4: merge FUSED + BN stats (PER-BATCH copies) + per-(n,o) max/min ----------------
// grid (8 b, 128 ntile-of-16) = 1024 blocks; blockIdx.x = b -> XCD pin.
// Atomics go to stats[b][o]: per-address chain = 128 blocks (was 512/1024 global ->
// serialized-RMW critical path; R9 vs R11 delta matched chain-length scaling), and the
// RMW stays in the local XCD's L2. 2-q unroll keeps 18+2 loads in flight per step.
__global__ __launch_bounds__(256) void stats2_kernel(float* __restrict__ p,
                                                     const float* __restrict__ q,
                                                     const float* __restrict__ pd,
                                                     const int* __restrict__ pi,
                                                     float* __restrict__ stats,
                                                     float* __restrict__ hmn) {
    __shared__ int idx_s[16 * KNN];
    const int b = blockIdx.x, n0 = blockIdx.y * 16;
    const int o = threadIdx.x;
    if (threadIdx.x < 16) {
        size_t g = (size_t)(b * NPTS + n0 + threadIdx.x) * 36;
        const float* d = pd + g;
        const int*   i = pi + g;
        int p0 = 0, p1 = 0, p2 = 0, p3 = 0;
#pragma unroll
        for (int k = 0; k < KNN; ++k) {
            float v0 = (p0 < KNN) ? d[p0]      : FLT_MAX;
            float v1 = (p1 < KNN) ? d[9 + p1]  : FLT_MAX;
            float v2 = (p2 < KNN) ? d[18 + p2] : FLT_MAX;
            float v3 = (p3 < KNN) ? d[27 + p3] : FLT_MAX;
            float best = v0; int sel = 0;
            if (v1 < best) { best = v1; sel = 1; }
            if (v2 < best) { best = v2; sel = 2; }
            if (v3 < best) { best = v3; sel = 3; }
            int idx;
            if      (sel == 0) { idx = i[p0];      p0++; }
            else if (sel == 1) { idx = i[9 + p1];  p1++; }
            else if (sel == 2) { idx = i[18 + p2]; p2++; }
            else               { idx = i[27 + p3]; p3++; }
            idx_s[threadIdx.x * KNN + k] = idx;
        }
    }
    __syncthreads();
    const float* qb = q + (size_t)b * NPTS * NOUT + o;
    float s = 0.f, ss = 0.f;
    for (int qq = 0; qq < 16; qq += 2) {
        size_t off0 = (size_t)(b * NPTS + n0 + qq) * NOUT + o;
        size_t off1 = off0 + NOUT;
        float pv0 = p[off0], pv1 = p[off1];
        float h0[KNN], h1[KNN];
#pragma unroll
        for (int k = 0; k < KNN; ++k)
            h0[k] = qb[(size_t)idx_s[qq * KNN + k] * NOUT];
#pragma unroll
        for (int k = 0; k < KNN; ++k)
            h1[k] = qb[(size_t)idx_s[(qq + 1) * KNN + k] * NOUT];
        float mx0 = -FLT_MAX, mn0 = FLT_MAX, mx1 = -FLT_MAX, mn1 = FLT_MAX;
#pragma unroll
        for (int k = 0; k < KNN; ++k) {
            float a = pv0 + h0[k], c = pv1 + h1[k];
            s += a + c; ss += a * a + c * c;
            mx0 = fmaxf(mx0, a); mn0 = fminf(mn0, a);
            mx1 = fmaxf(mx1, c); mn1 = fminf(mn1, c);
        }
        p[off0] = mx0; hmn[off0] = mn0;
        p[off1] = mx1; hmn[off1] = mn1;
    }
    atomicAdd(&stats[b * 512 + o], s);
    atomicAdd(&stats[b * 512 + NOUT + o], ss);
}

// ---------------- kernel 5: normalize + relu + max_k, transposed store ----------------
// grid (8 b, 128 ntile-of-16); blockIdx.x = b -> XCD pin. Sums the 8 per-batch stat copies.
__global__ __launch_bounds__(256) void final_kernel(const float* __restrict__ hmx,
                                                    const float* __restrict__ hmn,
                                                    const float* __restrict__ stats,
                                                    const float* __restrict__ gamma,
                                                    const float* __restrict__ beta,
                                                    float* __restrict__ out) {
    __shared__ float tr[256 * 17];
    const int b = blockIdx.x, n0 = blockIdx.y * 16;
    const int o = threadIdx.x;
    float sum = 0.f, sumsq = 0.f;
#pragma unroll
    for (int i = 0; i < 8; ++i) {
        sum   += stats[i * 512 + o];
        sumsq += stats[i * 512 + NOUT + o];
    }
    const float inv = 1.f / (float)TOTCNT;
    float mean = sum * inv;
    float var  = sumsq * inv - mean * mean;
    float g    = gamma[o] / sqrtf(var + 1e-5f);
    float bet  = beta[o];
    const float* src = (g >= 0.f) ? hmx : hmn;
    for (int qq = 0; qq < 16; ++qq) {
        size_t off = (size_t)(b * NPTS + n0 + qq) * NOUT + o;
        float hn = (src[off] - mean) * g + bet;
        tr[o * 17 + qq] = fmaxf(hn, 0.f);
    }
    __syncthreads();
    int oo = threadIdx.x >> 4, qq = threadIdx.x & 15;
    for (int pass = 0; pass < 16; ++pass) {
        int o_ = pass * 16 + oo;
        out[((size_t)b * NOUT + o_) * NPTS + n0 + qq] = tr[o_ * 17 + qq];
    }
}

extern "C" void kernel_launch(void* const* d_in, const int* in_sizes, int n_in,
                              void* d_out, int out_size, void* d_ws, size_t ws_size,
                              hipStream_t stream) {
    (void)in_sizes; (void)n_in; (void)out_size; (void)ws_size;
    const float* x     = (const float*)d_in[0];
    const float* W     = (const float*)d_in[1];
    const float* gamma = (const float*)d_in[2];
    const float* beta  = (const float*)d_in[3];
    float* out = (float*)d_out;

    char* ws = (char*)d_ws;
    // [0,16M)  p  -> becomes hmax in stats2 (in-place)
    // [16,32M) q  (fp32)
    // [32,48M) knn/pq scratch (xhi,xlo,whi,wlo) -> dead by stats2, reused as hmn
    // [48M+)   pd, pi (live into stats2), sqh, stats[8][512]
    float*          p     = (float*)ws;
    float*          q     = (float*)(ws + (16u << 20));
    unsigned short* xhi   = (unsigned short*)(ws + (32u << 20));          // 4 MB
    unsigned short* xlo   = (unsigned short*)(ws + (36u << 20));          // 4 MB
    unsigned short* whi   = (unsigned short*)(ws + (40u << 20));          // 128 KB
    unsigned short* wlo   = (unsigned short*)(ws + (40u << 20) + 131072); // 128 KB
    float*          hmn   = (float*)(ws + (32u << 20));                   // 16 MB overlay
    float*          pd    = (float*)(ws + (48u << 20));                   // 2.25 MB
    int*            pi    = (int*)  (ws + (51u << 20));                   // 2.25 MB
    float*          sqh   = (float*)(ws + (54u << 20));                   // 64 KB
    float*          stats = (float*)(ws + (54u << 20) + 65536);           // 16 KB

    hipMemsetAsync(stats, 0, 8 * 512 * sizeof(float), stream);
    prep_kernel  <<<dim3(8, 33),    256, 0, stream>>>(x, W, xhi, xlo, whi, wlo, sqh);
    knn_mfma     <<<dim3(8, 32, 4), 256, 0, stream>>>(xhi, xlo, sqh, pd, pi);
    pq_mfma      <<<dim3(8, 8, 8),  256, 0, stream>>>(xhi, xlo, whi, wlo, p, q);
    stats2_kernel<<<dim3(8, 128),   256, 0, stream>>>(p, q, pd, pi, stats, hmn);
    final_kernel <<<dim3(8, 128),   256, 0, stream>>>(p, hmn, stats, gamma, beta, out);
}

// Round 13
// 211.929 us; speedup vs baseline: 1.4762x; 1.0055x over previous
//
#include <hip/hip_runtime.h>
#include <float.h>
#include <math.h>

#define BATCH 8
#define CHN   128
#define NPTS  2048
#define KNN   9
#define NOUT  256
#define TOTCNT (BATCH*NPTS*KNN)

typedef __attribute__((ext_vector_type(8))) short short8;
typedef __attribute__((ext_vector_type(4))) float f32x4;

__device__ __forceinline__ unsigned short f2bf(float f) {
    unsigned int u = __float_as_uint(f);
    unsigned int r = (u + 0x7FFFu + ((u >> 16) & 1u)) >> 16;
    return (unsigned short)r;
}
__device__ __forceinline__ float bf2f(unsigned short h) {
    return __uint_as_float(((unsigned int)h) << 16);
}

// ---------------- kernel 1: transpose + bf16 split + 0.5*sqnorm  (+ fused W split) ----------------
// grid (8 b, 33): y<32 -> x prep tiles (XCD pin via blockIdx.x=b); y==32 -> W split (8-way partition)
__global__ __launch_bounds__(256) void prep_kernel(const float* __restrict__ x,
                                                   const float* __restrict__ W,
                                                   unsigned short* __restrict__ xhi,
                                                   unsigned short* __restrict__ xlo,
                                                   unsigned short* __restrict__ whi,
                                                   unsigned short* __restrict__ wlo,
                                                   float* __restrict__ sqh) {
    __shared__ float xt[128 * 65];
    __shared__ float psq[256];
    const int b = blockIdx.x, tid = threadIdx.x;
    if (blockIdx.y == 32) {   // W -> Bcat=[W1-W2; W2] hi/lo split; rows b*64..b*64+63
#pragma unroll
        for (int e = 0; e < 32; ++e) {
            int idx = e * 256 + tid;
            int r = b * 64 + (idx >> 7), c = idx & 127;
            float v = (r < 256) ? (W[r * 256 + c] - W[r * 256 + 128 + c])
                                : W[(r - 256) * 256 + 128 + c];
            unsigned short h = f2bf(v);
            float hf = bf2f(h);
            whi[r * 128 + c] = h;
            wlo[r * 128 + c] = f2bf(v - hf);
        }
        return;
    }
    const int n0 = blockIdx.y * 64;
#pragma unroll 4
    for (int p = 0; p < 32; ++p) {
        int c = p * 4 + (tid >> 6), n = tid & 63;
        xt[c * 65 + n] = x[((size_t)b * CHN + c) * NPTS + n0 + n];
    }
    __syncthreads();
    const int n = tid >> 2, cq = tid & 3;
    size_t row = (size_t)(b * NPTS + n0 + n) * CHN;
    float s = 0.f;
#pragma unroll 8
    for (int j = 0; j < 32; ++j) {
        int c = cq * 32 + j;
        float f = xt[c * 65 + n];
        unsigned short h = f2bf(f);
        float hf = bf2f(h);
        unsigned short l = f2bf(f - hf);
        xhi[row + c] = h;
        xlo[row + c] = l;
        s += f * f;
    }
    psq[tid] = s;
    __syncthreads();
    if (tid < 64)
        sqh[b * NPTS + n0 + tid] =
            0.5f * (psq[tid*4] + psq[tid*4+1] + psq[tid*4+2] + psq[tid*4+3]);
}

// ---------------- kernel 2: MFMA split-bf16 distance + top-9 (R7 structure — FROZEN) ----------------
__global__ __launch_bounds__(256) void knn_mfma(const unsigned short* __restrict__ xhi,
                                                const unsigned short* __restrict__ xlo,
                                                const float* __restrict__ sqh,
                                                float* __restrict__ pd,
                                                int* __restrict__ pi) {
    __shared__ __align__(16) float dts[64 * 132];   // 33792 B

    const int tid = threadIdx.x;
    const int b = blockIdx.x, q0 = blockIdx.y * 64, ms = blockIdx.z;
    const int msbase = ms * 512;
    const int wv = tid >> 6, lane = tid & 63;
    const int quad = lane >> 4, col = lane & 15;
    const int koff = quad * 8;
    const int mcol0 = wv * 32;
    const size_t xb = (size_t)b * NPTS * CHN;

    float dl[KNN]; int il[KNN];
#pragma unroll
    for (int k = 0; k < KNN; ++k) { dl[k] = FLT_MAX; il[k] = 0; }

    const int qsc = tid >> 2, ss = tid & 3;
    const int cb = ss * 32;

    auto ins = [&](float v, int idx) {
        if (v < dl[KNN - 1]) {
            bool c0b = v < dl[0];
#pragma unroll
            for (int k = KNN - 1; k >= 1; --k) {
                bool sh   = v < dl[k - 1];
                bool here = v < dl[k];
                float nd = sh ? dl[k - 1] : (here ? v : dl[k]);
                int   ni = sh ? il[k - 1] : (here ? idx : il[k]);
                dl[k] = nd; il[k] = ni;
            }
            if (c0b) { dl[0] = v; il[0] = idx; }
        }
    };

    for (int iter = 0; iter < 4; ++iter) {
        const int mbase = msbase + iter * 128;
        float sm[2];
#pragma unroll
        for (int j = 0; j < 2; ++j)
            sm[j] = sqh[b * NPTS + mbase + mcol0 + j * 16 + col];

        f32x4 acc[4][2];
#pragma unroll
        for (int i = 0; i < 4; ++i)
#pragma unroll
            for (int j = 0; j < 2; ++j) acc[i][j] = (f32x4)0.f;

        for (int chk = 0; chk < 4; ++chk) {
            short8 ah[4], al[4];
#pragma unroll
            for (int i = 0; i < 4; ++i) {
                size_t g = xb + (size_t)(q0 + i * 16 + col) * CHN + chk * 32 + koff;
                ah[i] = *(const short8*)&xhi[g];
                al[i] = *(const short8*)&xlo[g];
            }
#pragma unroll
            for (int j = 0; j < 2; ++j) {
                size_t g = xb + (size_t)(mbase + mcol0 + j * 16 + col) * CHN + chk * 32 + koff;
                short8 bh = *(const short8*)&xhi[g];
                short8 bl = *(const short8*)&xlo[g];
#pragma unroll
                for (int i = 0; i < 4; ++i) {
                    acc[i][j] = __builtin_amdgcn_mfma_f32_16x16x32_bf16(ah[i], bh, acc[i][j], 0, 0, 0);
                    acc[i][j] = __builtin_amdgcn_mfma_f32_16x16x32_bf16(ah[i], bl, acc[i][j], 0, 0, 0);
                    acc[i][j] = __builtin_amdgcn_mfma_f32_16x16x32_bf16(al[i], bh, acc[i][j], 0, 0, 0);
                }
            }
        }

        __syncthreads();
#pragma unroll
        for (int j = 0; j < 2; ++j)
#pragma unroll
            for (int i = 0; i < 4; ++i)
#pragma unroll
                for (int r = 0; r < 4; ++r) {
                    int q_ = i * 16 + quad * 4 + r;
                    dts[q_ * 132 + mcol0 + j * 16 + col] = sm[j] - acc[i][j][r];
                }
        __syncthreads();
        const int ibase = mbase + cb;
#pragma unroll
        for (int jj = 0; jj < 8; ++jj) {
            float4 v = *(const float4*)&dts[qsc * 132 + cb + jj * 4];
            float mn4 = fminf(fminf(v.x, v.y), fminf(v.z, v.w));
            if (mn4 < dl[KNN - 1]) {
                int ib = ibase + jj * 4;
                ins(v.x, ib); ins(v.y, ib + 1); ins(v.z, ib + 2); ins(v.w, ib + 3);
            }
        }
    }

    __syncthreads();
    float* md = dts;
    int*   mi = (int*)(dts + 2304);
#pragma unroll
    for (int k = 0; k < KNN; ++k) {
        md[qsc * 36 + ss * 9 + k] = dl[k];
        mi[qsc * 36 + ss * 9 + k] = il[k];
    }
    __syncthreads();
    if (tid < 64) {
        int base = tid * 36;
        int p0 = 0, p1 = 0, p2 = 0, p3 = 0;
        size_t ob = ((size_t)(b * NPTS + q0 + tid) * 4 + ms) * KNN;
        for (int k = 0; k < KNN; ++k) {
            float v0 = (p0 < KNN) ? md[base + p0]      : FLT_MAX;
            float v1 = (p1 < KNN) ? md[base + 9 + p1]  : FLT_MAX;
            float v2 = (p2 < KNN) ? md[base + 18 + p2] : FLT_MAX;
            float v3 = (p3 < KNN) ? md[base + 27 + p3] : FLT_MAX;
            float best = v0; int sel = 0;
            if (v1 < best) { best = v1; sel = 1; }
            if (v2 < best) { best = v2; sel = 2; }
            if (v3 < best) { best = v3; sel = 3; }
            int idx;
            if      (sel == 0) { idx = mi[base + p0];      p0++; }
            else if (sel == 1) { idx = mi[base + 9 + p1];  p1++; }
            else if (sel == 2) { idx = mi[base + 18 + p2]; p2++; }
            else               { idx = mi[base + 27 + p3]; p3++; }
            pd[ob + k] = best;
            pi[ob + k] = idx;
        }
    }
}

// ---------------- kernel 3: p = x*(W1-W2)^T (fp32), q = x*W2^T (bf16) via MFMA ----------------
// grid (8 b, 8 ntile-of-256, 8 otile-of-64); blockIdx.x = b -> XCD pin. No LDS, no barriers.
// q stored bf16 (R10-proven: absmax 0.031, not the regression cause) — pq W 32->24 MB,
// stats2 gathers 2 B/lane.
__global__ __launch_bounds__(256) void pq_mfma(const unsigned short* __restrict__ xhi,
                                               const unsigned short* __restrict__ xlo,
                                               const unsigned short* __restrict__ whi,
                                               const unsigned short* __restrict__ wlo,
                                               float* __restrict__ p,
                                               unsigned short* __restrict__ q) {
    const int tid = threadIdx.x;
    const int b = blockIdx.x, nt = blockIdx.y, ot = blockIdx.z;
    const int wv = tid >> 6, lane = tid & 63;
    const int quad = lane >> 4, col = lane & 15;
    const int koff = quad * 8;
    const size_t xb = (size_t)b * NPTS * CHN;
    const int nbase = nt * 256 + wv * 64;
    const int obase = ot * 64;

    f32x4 acc[4][4];
#pragma unroll
    for (int i = 0; i < 4; ++i)
#pragma unroll
        for (int j = 0; j < 4; ++j) acc[i][j] = (f32x4)0.f;

    for (int chk = 0; chk < 4; ++chk) {
        short8 ah[4], al[4];
#pragma unroll
        for (int i = 0; i < 4; ++i) {
            size_t g = xb + (size_t)(nbase + i * 16 + col) * CHN + chk * 32 + koff;
            ah[i] = *(const short8*)&xhi[g];
            al[i] = *(const short8*)&xlo[g];
        }
#pragma unroll
        for (int j = 0; j < 4; ++j) {
            size_t g = (size_t)(obase + j * 16 + col) * CHN + chk * 32 + koff;
            short8 bh = *(const short8*)&whi[g];
            short8 bl = *(const short8*)&wlo[g];
#pragma unroll
            for (int i = 0; i < 4; ++i) {
                acc[i][j] = __builtin_amdgcn_mfma_f32_16x16x32_bf16(ah[i], bh, acc[i][j], 0, 0, 0);
                acc[i][j] = __builtin_amdgcn_mfma_f32_16x16x32_bf16(ah[i], bl, acc[i][j], 0, 0, 0);
                acc[i][j] = __builtin_amdgcn_mfma_f32_16x16x32_bf16(al[i], bh, acc[i][j], 0, 0, 0);
            }
        }
    }
#pragma unroll
    for (int i = 0; i < 4; ++i)
#pragma unroll
        for (int j = 0; j < 4; ++j) {
            int oc = (obase + j * 16 + col) & 255;
#pragma unroll
            for (int r = 0; r < 4; ++r) {
                int n = nbase + i * 16 + quad * 4 + r;
                size_t off = (size_t)(b * NPTS + n) * NOUT + oc;
                if (ot < 4) p[off] = acc[i][j][r];
                else        q[off] = f2bf(acc[i][j][r]);
            }
        }
}

// ---------------- kernel 4: merge FUSED + BN stats (per-batch) + packed bf16 (hmax,hmin) ----------------
// grid (8 b, 128 ntile-of-16) = 1024 blocks; blockIdx.x = b -> XCD pin.
// Writes ONE u32 per (n,o): (bf16(hmax)<<16)|bf16(hmin) -> 16 MB instead of 32, p untouched.
// Per-batch stat copies: atomic chain 128 blocks, XCD-local L2 RMW (R12-proven).
__global__ __launch_bounds__(256) void stats2_kernel(const float* __restrict__ p,
                                                     const unsigned short* __restrict__ q,
                                                     const float* __restrict__ pd,
                                                     const int* __restrict__ pi,
                                                     float* __restrict__ stats,
                                                     unsigned int* __restrict__ hmm) {
    __shared__ int idx_s[16 * KNN];
    const int b = blockIdx.x, n0 = blockIdx.y * 16;
    const int o = threadIdx.x;
    if (threadIdx.x < 16) {
        size_t g = (size_t)(b * NPTS + n0 + threadIdx.x) * 36;
        const float* d = pd + g;
        const int*   i = pi + g;
        int p0 = 0, p1 = 0, p2 = 0, p3 = 0;
#pragma unroll
        for (int k = 0; k < KNN; ++k) {
            float v0 = (p0 < KNN) ? d[p0]      : FLT_MAX;
            float v1 = (p1 < KNN) ? d[9 + p1]  : FLT_MAX;
            float v2 = (p2 < KNN) ? d[18 + p2] : FLT_MAX;
            float v3 = (p3 < KNN) ? d[27 + p3] : FLT_MAX;
            float best = v0; int sel = 0;
            if (v1 < best) { best = v1; sel = 1; }
            if (v2 < best) { best = v2; sel = 2; }
            if (v3 < best) { best = v3; sel = 3; }
            int idx;
            if      (sel == 0) { idx = i[p0];      p0++; }
            else if (sel == 1) { idx = i[9 + p1];  p1++; }
            else if (sel == 2) { idx = i[18 + p2]; p2++; }
            else               { idx = i[27 + p3]; p3++; }
            idx_s[threadIdx.x * KNN + k] = idx;
        }
    }
    __syncthreads();
    const unsigned short* qb = q + (size_t)b * NPTS * NOUT + o;
    float s = 0.f, ss = 0.f;
    for (int qq = 0; qq < 16; qq += 2) {
        size_t off0 = (size_t)(b * NPTS + n0 + qq) * NOUT + o;
        size_t off1 = off0 + NOUT;
        float pv0 = p[off0], pv1 = p[off1];
        float h0[KNN], h1[KNN];
#pragma unroll
        for (int k = 0; k < KNN; ++k)
            h0[k] = bf2f(qb[(size_t)idx_s[qq * KNN + k] * NOUT]);
#pragma unroll
        for (int k = 0; k < KNN; ++k)
            h1[k] = bf2f(qb[(size_t)idx_s[(qq + 1) * KNN + k] * NOUT]);
        float mx0 = -FLT_MAX, mn0 = FLT_MAX, mx1 = -FLT_MAX, mn1 = FLT_MAX;
#pragma unroll
        for (int k = 0; k < KNN; ++k) {
            float a = pv0 + h0[k], c = pv1 + h1[k];
            s += a + c; ss += a * a + c * c;
            mx0 = fmaxf(mx0, a); mn0 = fminf(mn0, a);
            mx1 = fmaxf(mx1, c); mn1 = fminf(mn1, c);
        }
        hmm[off0] = ((unsigned int)f2bf(mx0) << 16) | f2bf(mn0);
        hmm[off1] = ((unsigned int)f2bf(mx1) << 16) | f2bf(mn1);
    }
    atomicAdd(&stats[b * 512 + o], s);
    atomicAdd(&stats[b * 512 + NOUT + o], ss);
}

// ---------------- kernel 5: normalize + relu + max_k, transposed store ----------------
// grid (8 b, 128 ntile-of-16); blockIdx.x = b -> XCD pin. Reads only the 16 MB packed buffer.
__global__ __launch_bounds__(256) void final_kernel(const unsigned int* __restrict__ hmm,
                                                    const float* __restrict__ stats,
                                                    const float* __restrict__ gamma,
                                                    const float* __restrict__ beta,
                                                    float* __restrict__ out) {
    __shared__ float tr[256 * 17];
    const int b = blockIdx.x, n0 = blockIdx.y * 16;
    const int o = threadIdx.x;
    float sum = 0.f, sumsq = 0.f;
#pragma unroll
    for (int i = 0; i < 8; ++i) {
        sum   += stats[i * 512 + o];
        sumsq += stats[i * 512 + NOUT + o];
    }
    const float inv = 1.f / (float)TOTCNT;
    float mean = sum * inv;
    float var  = sumsq * inv - mean * mean;
    float g    = gamma[o] / sqrtf(var + 1e-5f);
    float bet  = beta[o];
    const bool pos = (g >= 0.f);
    for (int qq = 0; qq < 16; ++qq) {
        size_t off = (size_t)(b * NPTS + n0 + qq) * NOUT + o;
        unsigned int w = hmm[off];
        float v = bf2f(pos ? (unsigned short)(w >> 16) : (unsigned short)(w & 0xFFFFu));
        float hn = (v - mean) * g + bet;
        tr[o * 17 + qq] = fmaxf(hn, 0.f);
    }
    __syncthreads();
    int oo = threadIdx.x >> 4, qq = threadIdx.x & 15;
    for (int pass = 0; pass < 16; ++pass) {
        int o_ = pass * 16 + oo;
        out[((size_t)b * NOUT + o_) * NPTS + n0 + qq] = tr[o_ * 17 + qq];
    }
}

extern "C" void kernel_launch(void* const* d_in, const int* in_sizes, int n_in,
                              void* d_out, int out_size, void* d_ws, size_t ws_size,
                              hipStream_t stream) {
    (void)in_sizes; (void)n_in; (void)out_size; (void)ws_size;
    const float* x     = (const float*)d_in[0];
    const float* W     = (const float*)d_in[1];
    const float* gamma = (const float*)d_in[2];
    const float* beta  = (const float*)d_in[3];
    float* out = (float*)d_out;

    char* ws = (char*)d_ws;
    // [0,16M)   p (fp32, read-only after pq)
    // [16,24M)  q (bf16)
    // [24,28M)  xhi   [28,32M) xlo        -> dead after pq
    // [32,48M)  hmm packed u32 (stats2 output; region free of live data by then)
    // [48M+)    whi, wlo, pd, pi, sqh, stats[8][512]
    float*          p     = (float*)ws;
    unsigned short* q     = (unsigned short*)(ws + (16u << 20));
    unsigned short* xhi   = (unsigned short*)(ws + (24u << 20));          // 4 MB
    unsigned short* xlo   = (unsigned short*)(ws + (28u << 20));          // 4 MB
    unsigned int*   hmm   = (unsigned int*)(ws + (32u << 20));            // 16 MB
    unsigned short* whi   = (unsigned short*)(ws + (48u << 20));          // 128 KB
    unsigned short* wlo   = (unsigned short*)(ws + (48u << 20) + 131072); // 128 KB
    float*          pd    = (float*)(ws + (49u << 20));                   // 2.25 MB
    int*            pi    = (int*)  (ws + (52u << 20));                   // 2.25 MB
    float*          sqh   = (float*)(ws + (55u << 20));                   // 64 KB
    float*          stats = (float*)(ws + (55u << 20) + 65536);           // 16 KB

    hipMemsetAsync(stats, 0, 8 * 512 * sizeof(float), stream);
    prep_kernel  <<<dim3(8, 33),    256, 0, stream>>>(x, W, xhi, xlo, whi, wlo, sqh);
    knn_mfma     <<<dim3(8, 32, 4), 256, 0, stream>>>(xhi, xlo, sqh, pd, pi);
    pq_mfma      <<<dim3(8, 8, 8),  256, 0, stream>>>(xhi, xlo, whi, wlo, p, q);
    stats2_kernel<<<dim3(8, 128),   256, 0, stream>>>(p, q, pd, pi, stats, hmm);
    final_kernel <<<dim3(8, 128),   256, 0, stream>>>(hmm, stats, gamma, beta, out);
}